// Round 1
// baseline (372.786 us; speedup 1.0000x reference)
//
#include <hip/hip_runtime.h>
#include <stdint.h>

#define NN 50000
#define NE 600000
#define DD 128
#define BN_EPS 1e-5f

typedef __attribute__((ext_vector_type(8))) short short8;
typedef __attribute__((ext_vector_type(4))) float f32x4;

__device__ __forceinline__ float bf2f(uint16_t u) {
    union { uint32_t u; float f; } v; v.u = ((uint32_t)u) << 16; return v.f;
}
__device__ __forceinline__ uint16_t f2bf(float f) {
    union { float f; uint32_t u; } v; v.f = f;
    return (uint16_t)((v.u + 0x7FFFu + ((v.u >> 16) & 1u)) >> 16);
}

// ---------------- CSR build ----------------
__global__ void k_count(const int* __restrict__ col, int* __restrict__ cnt) {
    int e = blockIdx.x * 256 + threadIdx.x;
    if (e < NE) atomicAdd(&cnt[col[e]], 1);
}

__global__ void k_bsum(const int* __restrict__ cnt, int* __restrict__ bsum) {
    __shared__ int s[256];
    int i = blockIdx.x * 256 + threadIdx.x;
    s[threadIdx.x] = (i < NN) ? cnt[i] : 0;
    __syncthreads();
    for (int d = 128; d > 0; d >>= 1) {
        if (threadIdx.x < d) s[threadIdx.x] += s[threadIdx.x + d];
        __syncthreads();
    }
    if (threadIdx.x == 0) bsum[blockIdx.x] = s[0];
}

__global__ void k_bscan(int* __restrict__ bsum, int nb) {
    __shared__ int s[256];
    int t = threadIdx.x;
    int v = (t < nb) ? bsum[t] : 0;
    s[t] = v;
    __syncthreads();
    for (int d = 1; d < 256; d <<= 1) {
        int add = (t >= d) ? s[t - d] : 0;
        __syncthreads();
        s[t] += add;
        __syncthreads();
    }
    if (t < nb) bsum[t] = s[t] - v;  // exclusive
}

__global__ void k_off(const int* __restrict__ cnt, const int* __restrict__ bsum,
                      int* __restrict__ off, float* __restrict__ deginv,
                      float* __restrict__ dis) {
    __shared__ int s[256];
    int t = threadIdx.x;
    int i = blockIdx.x * 256 + t;
    int v = (i < NN) ? cnt[i] : 0;
    s[t] = v;
    __syncthreads();
    for (int d = 1; d < 256; d <<= 1) {
        int add = (t >= d) ? s[t - d] : 0;
        __syncthreads();
        s[t] += add;
        __syncthreads();
    }
    if (i < NN) {
        int excl = s[t] - v + bsum[blockIdx.x];
        off[i] = excl;
        deginv[i] = 1.0f / fmaxf((float)v, 1.0f);       // ClusterGCN 1/deg
        dis[i] = rsqrtf((float)v + 1.0f);               // SGConv D^{-1/2} incl self-loop
        if (i == NN - 1) off[NN] = excl + v;
    }
}

__global__ void k_fill(const int* __restrict__ ei, const int* __restrict__ off,
                       int* __restrict__ fill, int* __restrict__ csr_row) {
    int e = blockIdx.x * 256 + threadIdx.x;
    if (e < NE) {
        int c = ei[NE + e];
        int p = atomicAdd(&fill[c], 1);
        csr_row[off[c] + p] = ei[e];
    }
}

// ---------------- gather + fp32->bf16 ----------------
__global__ void k_gather(const int* __restrict__ x_idx, const float* __restrict__ emb,
                         uint16_t* __restrict__ xb) {
    int idx = blockIdx.x * 256 + threadIdx.x;  // NN*32 threads, 4 elems each
    if (idx >= NN * 32) return;
    int node = idx >> 5, c4 = (idx & 31) << 2;
    int src = x_idx[node];
    float4 v = *(const float4*)(emb + (size_t)src * DD + c4);
    ushort4 o;
    o.x = f2bf(v.x); o.y = f2bf(v.y); o.z = f2bf(v.z); o.w = f2bf(v.w);
    *(ushort4*)(xb + (size_t)node * DD + c4) = o;
}

// ---------------- aggregation (1 wave = 1 node) ----------------
// MODE 0: agg[c] = deginv[c] * sum_e x[row_e]
// MODE 1: agg[c] = dis[c] * (sum_e x[row_e]*dis[row_e] + x[c]*dis[c])
template<int MODE>
__global__ void k_agg(const uint16_t* __restrict__ xb, const int* __restrict__ off,
                      const int* __restrict__ csr_row, const float* __restrict__ deginv,
                      const float* __restrict__ dis, uint16_t* __restrict__ aggb) {
    int node = blockIdx.x * 4 + (threadIdx.x >> 6);
    if (node >= NN) return;
    int lane = threadIdx.x & 63;
    float a0 = 0.0f, a1 = 0.0f;
    float sc;
    if (MODE == 1) {
        sc = dis[node];
        uint32_t v = *(const uint32_t*)(xb + (size_t)node * DD + lane * 2);
        a0 = sc * bf2f((uint16_t)(v & 0xFFFFu));
        a1 = sc * bf2f((uint16_t)(v >> 16));
    } else {
        sc = deginv[node];
    }
    int s = off[node], e = off[node + 1];
    for (int i = s; i < e; ++i) {
        int r = csr_row[i];
        uint32_t v = *(const uint32_t*)(xb + (size_t)r * DD + lane * 2);
        float w = (MODE == 1) ? dis[r] : 1.0f;
        a0 += w * bf2f((uint16_t)(v & 0xFFFFu));
        a1 += w * bf2f((uint16_t)(v >> 16));
    }
    a0 *= sc; a1 *= sc;
    uint32_t o = (uint32_t)f2bf(a0) | ((uint32_t)f2bf(a1) << 16);
    *(uint32_t*)(aggb + (size_t)node * DD + lane * 2) = o;
}

// ---------------- MFMA GEMM: H = A1@W1^T (+ A2@W2^T) (+bias), BN stats ----------------
// A: [NN][128] bf16 row-major; W: [128 out][128 k] fp32 row-major (converted on stage).
// Tile 128 rows x 128 cols per 256-thread block; 4 waves in 2x2 of 64x64.
template<bool DUAL, bool STATS, bool BIAS>
__global__ __launch_bounds__(256, 2)
void k_gemm(const uint16_t* __restrict__ A1, const uint16_t* __restrict__ A2,
            const float* __restrict__ W1, const float* __restrict__ W2,
            const float* __restrict__ bias, float* __restrict__ H,
            float* __restrict__ stats) {
    __shared__ uint16_t Alds[128 * 128];
    __shared__ uint16_t Wlds[128 * 128];
    const int t = threadIdx.x;
    const int lane = t & 63, wid = t >> 6;
    const int wm = (wid >> 1) * 64, wn = (wid & 1) * 64;
    const int m0 = blockIdx.x * 128;
    f32x4 zero = {0.0f, 0.0f, 0.0f, 0.0f};
    f32x4 acc[4][4];
    #pragma unroll
    for (int m = 0; m < 4; ++m)
        #pragma unroll
        for (int n = 0; n < 4; ++n) acc[m][n] = zero;

    const int NP = DUAL ? 2 : 1;
    for (int p = 0; p < NP; ++p) {
        const uint16_t* A = (DUAL && p) ? A2 : A1;
        const float* W = (DUAL && p) ? W2 : W1;
        if (p) __syncthreads();
        // stage A tile: 2048 16B chunks, XOR-swizzled rows (G4)
        #pragma unroll
        for (int it = 0; it < 8; ++it) {
            int idx = it * 256 + t;
            int row = idx >> 4, c16 = idx & 15;
            uint32_t boff = (uint32_t)(row * 256 + ((c16 * 16) ^ ((row & 7) << 4)));
            uint4 v = make_uint4(0u, 0u, 0u, 0u);
            if (m0 + row < NN)
                v = *(const uint4*)(A + (size_t)(m0 + row) * DD + c16 * 8);
            *(uint4*)((char*)Alds + boff) = v;
        }
        // stage W tile: fp32 -> bf16, same swizzle
        #pragma unroll
        for (int it = 0; it < 8; ++it) {
            int idx = it * 256 + t;
            int row = idx >> 4, c8 = idx & 15;
            const float* wp = W + row * DD + c8 * 8;
            float4 v0 = *(const float4*)(wp);
            float4 v1 = *(const float4*)(wp + 4);
            uint4 pk;
            pk.x = (uint32_t)f2bf(v0.x) | ((uint32_t)f2bf(v0.y) << 16);
            pk.y = (uint32_t)f2bf(v0.z) | ((uint32_t)f2bf(v0.w) << 16);
            pk.z = (uint32_t)f2bf(v1.x) | ((uint32_t)f2bf(v1.y) << 16);
            pk.w = (uint32_t)f2bf(v1.z) | ((uint32_t)f2bf(v1.w) << 16);
            uint32_t boff = (uint32_t)(row * 256 + ((c8 * 16) ^ ((row & 7) << 4)));
            *(uint4*)((char*)Wlds + boff) = pk;
        }
        __syncthreads();
        #pragma unroll
        for (int ks = 0; ks < 4; ++ks) {
            short8 a[4], b[4];
            int kb = ks * 64 + ((lane >> 4) << 4);   // byte offset of this lane's 8 bf16
            #pragma unroll
            for (int m = 0; m < 4; ++m) {
                int row = wm + m * 16 + (lane & 15);
                a[m] = *(const short8*)((const char*)Alds + row * 256 + (kb ^ ((row & 7) << 4)));
            }
            #pragma unroll
            for (int n = 0; n < 4; ++n) {
                int row = wn + n * 16 + (lane & 15);
                b[n] = *(const short8*)((const char*)Wlds + row * 256 + (kb ^ ((row & 7) << 4)));
            }
            #pragma unroll
            for (int m = 0; m < 4; ++m)
                #pragma unroll
                for (int n = 0; n < 4; ++n)
                    acc[m][n] = __builtin_amdgcn_mfma_f32_16x16x32_bf16(a[m], b[n], acc[m][n], 0, 0, 0);
        }
    }
    // epilogue: bias, store, BN stats (sum/sumsq per channel)
    #pragma unroll
    for (int n = 0; n < 4; ++n) {
        int col = wn + n * 16 + (lane & 15);
        float bb = BIAS ? bias[col] : 0.0f;
        float ssum = 0.0f, ssq = 0.0f;
        #pragma unroll
        for (int m = 0; m < 4; ++m) {
            int rbase = m0 + wm + m * 16 + ((lane >> 4) << 2);
            #pragma unroll
            for (int i = 0; i < 4; ++i) {
                int gr = rbase + i;
                if (gr < NN) {
                    float v = acc[m][n][i] + bb;
                    H[(size_t)gr * DD + col] = v;
                    ssum += v; ssq += v * v;
                }
            }
        }
        if (STATS) {
            ssum += __shfl_xor(ssum, 16, 64);
            ssum += __shfl_xor(ssum, 32, 64);
            ssq  += __shfl_xor(ssq, 16, 64);
            ssq  += __shfl_xor(ssq, 32, 64);
            if (lane < 16) {
                atomicAdd(&stats[col], ssum);
                atomicAdd(&stats[DD + col], ssq);
            }
        }
    }
}

// ---------------- BN prep + apply ----------------
__global__ void k_bnprep(float* __restrict__ st, const float* __restrict__ gamma,
                         const float* __restrict__ beta) {
    int c = threadIdx.x;
    if (c < DD) {
        const float invn = 1.0f / (float)NN;
        float mean = st[c] * invn;
        float var = st[DD + c] * invn - mean * mean;
        float sc = gamma[c] * rsqrtf(var + BN_EPS);
        st[256 + c] = sc;
        st[384 + c] = beta[c] - mean * sc;
    }
}

__global__ void k_bnrelu(const float* __restrict__ H, const float* __restrict__ st,
                         uint16_t* __restrict__ xb) {
    int idx = blockIdx.x * 256 + threadIdx.x;
    if (idx >= NN * 32) return;
    int node = idx >> 5, c4 = (idx & 31) << 2;
    float4 v = *(const float4*)(H + (size_t)node * DD + c4);
    float r0 = fmaxf(v.x * st[256 + c4 + 0] + st[384 + c4 + 0], 0.0f);
    float r1 = fmaxf(v.y * st[256 + c4 + 1] + st[384 + c4 + 1], 0.0f);
    float r2 = fmaxf(v.z * st[256 + c4 + 2] + st[384 + c4 + 2], 0.0f);
    float r3 = fmaxf(v.w * st[256 + c4 + 3] + st[384 + c4 + 3], 0.0f);
    ushort4 o;
    o.x = f2bf(r0); o.y = f2bf(r1); o.z = f2bf(r2); o.w = f2bf(r3);
    *(ushort4*)(xb + (size_t)node * DD + c4) = o;
}

// ---------------- launch ----------------
extern "C" void kernel_launch(void* const* d_in, const int* in_sizes, int n_in,
                              void* d_out, int out_size, void* d_ws, size_t ws_size,
                              hipStream_t stream) {
    const int* x_idx   = (const int*)d_in[0];
    const int* ei      = (const int*)d_in[1];
    const float* emb   = (const float*)d_in[2];
    const float* W_out = (const float*)d_in[3];
    const float* W_root= (const float*)d_in[4];
    const float* g0    = (const float*)d_in[5];
    const float* be0   = (const float*)d_in[6];
    const float* W1    = (const float*)d_in[7];
    const float* b1    = (const float*)d_in[8];
    const float* g1    = (const float*)d_in[9];
    const float* be1   = (const float*)d_in[10];
    const float* W2    = (const float*)d_in[11];
    const float* b2    = (const float*)d_in[12];
    float* out = (float*)d_out;

    char* ws = (char*)d_ws;
    size_t o = 0;
    auto carve = [&](size_t bytes) -> void* {
        void* p = ws + o;
        o = (o + bytes + 255) & ~(size_t)255;
        return p;
    };
    int* cnt      = (int*)carve((size_t)NN * 4);
    int* fillp    = (int*)carve((size_t)NN * 4);
    int* off      = (int*)carve((size_t)(NN + 1) * 4);
    int* bsum     = (int*)carve(256 * 4);
    float* deginv = (float*)carve((size_t)NN * 4);
    float* dis    = (float*)carve((size_t)NN * 4);
    int* csr_row  = (int*)carve((size_t)NE * 4);
    uint16_t* xb  = (uint16_t*)carve((size_t)NN * DD * 2);
    uint16_t* aggb= (uint16_t*)carve((size_t)NN * DD * 2);
    float* st0    = (float*)carve(512 * 4);
    float* st1    = (float*)carve(512 * 4);

    hipMemsetAsync(cnt, 0, (size_t)NN * 4, stream);
    hipMemsetAsync(fillp, 0, (size_t)NN * 4, stream);
    hipMemsetAsync(st0, 0, 256 * 4, stream);
    hipMemsetAsync(st1, 0, 256 * 4, stream);

    const int EB = (NE + 255) / 256;
    const int NB = (NN + 255) / 256;        // 196
    const int GB = (NN + 127) / 128;        // 391 GEMM tiles
    const int AB = (NN + 3) / 4;            // 12500 agg blocks
    const int VB = (NN * 32 + 255) / 256;   // 6250 elementwise blocks

    k_count<<<EB, 256, 0, stream>>>(ei + NE, cnt);
    k_bsum<<<NB, 256, 0, stream>>>(cnt, bsum);
    k_bscan<<<1, 256, 0, stream>>>(bsum, NB);
    k_off<<<NB, 256, 0, stream>>>(cnt, bsum, off, deginv, dis);
    k_fill<<<EB, 256, 0, stream>>>(ei, off, fillp, csr_row);
    k_gather<<<VB, 256, 0, stream>>>(x_idx, emb, xb);

    // layer 0: ClusterGCN -> BN -> ReLU
    k_agg<0><<<AB, 256, 0, stream>>>(xb, off, csr_row, deginv, dis, aggb);
    k_gemm<true, true, false><<<GB, 256, 0, stream>>>(aggb, xb, W_out, W_root, nullptr, out, st0);
    k_bnprep<<<1, 128, 0, stream>>>(st0, g0, be0);
    k_bnrelu<<<VB, 256, 0, stream>>>(out, st0, xb);

    // layer 1: SGConv -> BN -> ReLU
    k_agg<1><<<AB, 256, 0, stream>>>(xb, off, csr_row, deginv, dis, aggb);
    k_gemm<false, true, true><<<GB, 256, 0, stream>>>(aggb, nullptr, W1, nullptr, b1, out, st1);
    k_bnprep<<<1, 128, 0, stream>>>(st1, g1, be1);
    k_bnrelu<<<VB, 256, 0, stream>>>(out, st1, xb);

    // layer 2: final SGConv -> d_out
    k_agg<1><<<AB, 256, 0, stream>>>(xb, off, csr_row, deginv, dis, aggb);
    k_gemm<false, false, true><<<GB, 256, 0, stream>>>(aggb, nullptr, W2, nullptr, b2, out, nullptr);
}

// Round 2
// 267.779 us; speedup vs baseline: 1.3921x; 1.3921x over previous
//
#include <hip/hip_runtime.h>
#include <stdint.h>

#define NN 50000
#define NE 600000
#define DD 128
#define BN_EPS 1e-5f

typedef __attribute__((ext_vector_type(8))) short short8;
typedef __attribute__((ext_vector_type(4))) float f32x4;

__device__ __forceinline__ float bf2f(uint16_t u) {
    union { uint32_t u; float f; } v; v.u = ((uint32_t)u) << 16; return v.f;
}
__device__ __forceinline__ uint16_t f2bf(float f) {
    union { float f; uint32_t u; } v; v.f = f;
    return (uint16_t)((v.u + 0x7FFFu + ((v.u >> 16) & 1u)) >> 16);
}
__device__ __forceinline__ float lo16(uint32_t v) { return bf2f((uint16_t)(v & 0xFFFFu)); }
__device__ __forceinline__ float hi16(uint32_t v) { return bf2f((uint16_t)(v >> 16)); }

// ---------------- CSR build ----------------
__global__ void k_count(const int* __restrict__ col, int* __restrict__ cnt) {
    int e = blockIdx.x * 256 + threadIdx.x;
    if (e < NE) atomicAdd(&cnt[col[e]], 1);
}

__global__ void k_bsum(const int* __restrict__ cnt, int* __restrict__ bsum) {
    __shared__ int s[256];
    int i = blockIdx.x * 256 + threadIdx.x;
    s[threadIdx.x] = (i < NN) ? cnt[i] : 0;
    __syncthreads();
    for (int d = 128; d > 0; d >>= 1) {
        if (threadIdx.x < d) s[threadIdx.x] += s[threadIdx.x + d];
        __syncthreads();
    }
    if (threadIdx.x == 0) bsum[blockIdx.x] = s[0];
}

__global__ void k_bscan(int* __restrict__ bsum, int nb) {
    __shared__ int s[256];
    int t = threadIdx.x;
    int v = (t < nb) ? bsum[t] : 0;
    s[t] = v;
    __syncthreads();
    for (int d = 1; d < 256; d <<= 1) {
        int add = (t >= d) ? s[t - d] : 0;
        __syncthreads();
        s[t] += add;
        __syncthreads();
    }
    if (t < nb) bsum[t] = s[t] - v;  // exclusive
}

__global__ void k_off(const int* __restrict__ cnt, const int* __restrict__ bsum,
                      int* __restrict__ off, float* __restrict__ deginv,
                      float* __restrict__ dis) {
    __shared__ int s[256];
    int t = threadIdx.x;
    int i = blockIdx.x * 256 + t;
    int v = (i < NN) ? cnt[i] : 0;
    s[t] = v;
    __syncthreads();
    for (int d = 1; d < 256; d <<= 1) {
        int add = (t >= d) ? s[t - d] : 0;
        __syncthreads();
        s[t] += add;
        __syncthreads();
    }
    if (i < NN) {
        int excl = s[t] - v + bsum[blockIdx.x];
        off[i] = excl;
        deginv[i] = 1.0f / fmaxf((float)v, 1.0f);       // ClusterGCN 1/deg
        dis[i] = rsqrtf((float)v + 1.0f);               // SGConv D^{-1/2} incl self-loop
        if (i == NN - 1) off[NN] = excl + v;
    }
}

__global__ void k_fill(const int* __restrict__ ei, const int* __restrict__ off,
                       int* __restrict__ fill, int* __restrict__ csr_row) {
    int e = blockIdx.x * 256 + threadIdx.x;
    if (e < NE) {
        int c = ei[NE + e];
        int p = atomicAdd(&fill[c], 1);
        csr_row[off[c] + p] = ei[e];
    }
}

// ---------------- gather + fp32->bf16 ----------------
__global__ void k_gather(const int* __restrict__ x_idx, const float* __restrict__ emb,
                         uint16_t* __restrict__ xb) {
    int idx = blockIdx.x * 256 + threadIdx.x;  // NN*32 threads, 4 elems each
    if (idx >= NN * 32) return;
    int node = idx >> 5, c4 = (idx & 31) << 2;
    int src = x_idx[node];
    float4 v = *(const float4*)(emb + (size_t)src * DD + c4);
    ushort4 o;
    o.x = f2bf(v.x); o.y = f2bf(v.y); o.z = f2bf(v.z); o.w = f2bf(v.w);
    *(ushort4*)(xb + (size_t)node * DD + c4) = o;
}

// ---------------- aggregation (1 wave = 1 node) ----------------
// MODE 0: agg[c] = deginv[c] * sum_e x[row_e]                       (x = xb, unscaled)
// MODE 1: agg[c] = dis[c] * (xs[c] + sum_e xs[row_e]), xs pre-scaled by dis on producer
// Index loads batched 64-wide + readlane broadcast (SGPR base addressing);
// gathers unrolled x4 for MLP.
template<int MODE>
__global__ __launch_bounds__(256)
void k_agg(const uint16_t* __restrict__ xb, const int* __restrict__ off,
           const int* __restrict__ csr_row, const float* __restrict__ deginv,
           const float* __restrict__ dis, uint16_t* __restrict__ aggb) {
    int node = blockIdx.x * 4 + (threadIdx.x >> 6);
    if (node >= NN) return;
    int lane = threadIdx.x & 63;
    const uint32_t* __restrict__ xw = (const uint32_t*)xb;
    float a0 = 0.0f, a1 = 0.0f;
    if (MODE == 1) {
        uint32_t v = xw[(size_t)node * 64 + lane];  // self term: xs[c]
        a0 = lo16(v); a1 = hi16(v);
    }
    int s = off[node], e = off[node + 1];
    for (int base = s; base < e; base += 64) {
        int cnt = min(e - base, 64);
        int idxv = (lane < cnt) ? csr_row[base + lane] : 0;
        int i = 0;
        for (; i + 4 <= cnt; i += 4) {
            int r0 = __builtin_amdgcn_readlane(idxv, i);
            int r1 = __builtin_amdgcn_readlane(idxv, i + 1);
            int r2 = __builtin_amdgcn_readlane(idxv, i + 2);
            int r3 = __builtin_amdgcn_readlane(idxv, i + 3);
            uint32_t v0 = xw[(size_t)r0 * 64 + lane];
            uint32_t v1 = xw[(size_t)r1 * 64 + lane];
            uint32_t v2 = xw[(size_t)r2 * 64 + lane];
            uint32_t v3 = xw[(size_t)r3 * 64 + lane];
            a0 += lo16(v0); a1 += hi16(v0);
            a0 += lo16(v1); a1 += hi16(v1);
            a0 += lo16(v2); a1 += hi16(v2);
            a0 += lo16(v3); a1 += hi16(v3);
        }
        for (; i < cnt; ++i) {
            int r = __builtin_amdgcn_readlane(idxv, i);
            uint32_t v = xw[(size_t)r * 64 + lane];
            a0 += lo16(v); a1 += hi16(v);
        }
    }
    float sc = (MODE == 1) ? dis[node] : deginv[node];
    a0 *= sc; a1 *= sc;
    uint32_t o = (uint32_t)f2bf(a0) | ((uint32_t)f2bf(a1) << 16);
    *(uint32_t*)(aggb + (size_t)node * DD + lane * 2) = o;
}

// ---------------- MFMA GEMM: H = A1@W1^T (+ A2@W2^T) (+bias), BN stats ----------------
template<bool DUAL, bool STATS, bool BIAS>
__global__ __launch_bounds__(256, 2)
void k_gemm(const uint16_t* __restrict__ A1, const uint16_t* __restrict__ A2,
            const float* __restrict__ W1, const float* __restrict__ W2,
            const float* __restrict__ bias, float* __restrict__ H,
            float* __restrict__ stats) {
    __shared__ uint16_t Alds[128 * 128];
    __shared__ uint16_t Wlds[128 * 128];
    const int t = threadIdx.x;
    const int lane = t & 63, wid = t >> 6;
    const int wm = (wid >> 1) * 64, wn = (wid & 1) * 64;
    const int m0 = blockIdx.x * 128;
    f32x4 zero = {0.0f, 0.0f, 0.0f, 0.0f};
    f32x4 acc[4][4];
    #pragma unroll
    for (int m = 0; m < 4; ++m)
        #pragma unroll
        for (int n = 0; n < 4; ++n) acc[m][n] = zero;

    const int NP = DUAL ? 2 : 1;
    for (int p = 0; p < NP; ++p) {
        const uint16_t* A = (DUAL && p) ? A2 : A1;
        const float* W = (DUAL && p) ? W2 : W1;
        if (p) __syncthreads();
        // stage A tile: 2048 16B chunks, XOR-swizzled rows (G4)
        #pragma unroll
        for (int it = 0; it < 8; ++it) {
            int idx = it * 256 + t;
            int row = idx >> 4, c16 = idx & 15;
            uint32_t boff = (uint32_t)(row * 256 + ((c16 * 16) ^ ((row & 7) << 4)));
            uint4 v = make_uint4(0u, 0u, 0u, 0u);
            if (m0 + row < NN)
                v = *(const uint4*)(A + (size_t)(m0 + row) * DD + c16 * 8);
            *(uint4*)((char*)Alds + boff) = v;
        }
        // stage W tile: fp32 -> bf16, same swizzle
        #pragma unroll
        for (int it = 0; it < 8; ++it) {
            int idx = it * 256 + t;
            int row = idx >> 4, c8 = idx & 15;
            const float* wp = W + row * DD + c8 * 8;
            float4 v0 = *(const float4*)(wp);
            float4 v1 = *(const float4*)(wp + 4);
            uint4 pk;
            pk.x = (uint32_t)f2bf(v0.x) | ((uint32_t)f2bf(v0.y) << 16);
            pk.y = (uint32_t)f2bf(v0.z) | ((uint32_t)f2bf(v0.w) << 16);
            pk.z = (uint32_t)f2bf(v1.x) | ((uint32_t)f2bf(v1.y) << 16);
            pk.w = (uint32_t)f2bf(v1.z) | ((uint32_t)f2bf(v1.w) << 16);
            uint32_t boff = (uint32_t)(row * 256 + ((c8 * 16) ^ ((row & 7) << 4)));
            *(uint4*)((char*)Wlds + boff) = pk;
        }
        __syncthreads();
        #pragma unroll
        for (int ks = 0; ks < 4; ++ks) {
            short8 a[4], b[4];
            int kb = ks * 64 + ((lane >> 4) << 4);   // byte offset of this lane's 8 bf16
            #pragma unroll
            for (int m = 0; m < 4; ++m) {
                int row = wm + m * 16 + (lane & 15);
                a[m] = *(const short8*)((const char*)Alds + row * 256 + (kb ^ ((row & 7) << 4)));
            }
            #pragma unroll
            for (int n = 0; n < 4; ++n) {
                int row = wn + n * 16 + (lane & 15);
                b[n] = *(const short8*)((const char*)Wlds + row * 256 + (kb ^ ((row & 7) << 4)));
            }
            #pragma unroll
            for (int m = 0; m < 4; ++m)
                #pragma unroll
                for (int n = 0; n < 4; ++n)
                    acc[m][n] = __builtin_amdgcn_mfma_f32_16x16x32_bf16(a[m], b[n], acc[m][n], 0, 0, 0);
        }
    }
    // epilogue: bias, store, BN stats (sum/sumsq per channel)
    #pragma unroll
    for (int n = 0; n < 4; ++n) {
        int col = wn + n * 16 + (lane & 15);
        float bb = BIAS ? bias[col] : 0.0f;
        float ssum = 0.0f, ssq = 0.0f;
        #pragma unroll
        for (int m = 0; m < 4; ++m) {
            int rbase = m0 + wm + m * 16 + ((lane >> 4) << 2);
            #pragma unroll
            for (int i = 0; i < 4; ++i) {
                int gr = rbase + i;
                if (gr < NN) {
                    float v = acc[m][n][i] + bb;
                    H[(size_t)gr * DD + col] = v;
                    ssum += v; ssq += v * v;
                }
            }
        }
        if (STATS) {
            ssum += __shfl_xor(ssum, 16, 64);
            ssum += __shfl_xor(ssum, 32, 64);
            ssq  += __shfl_xor(ssq, 16, 64);
            ssq  += __shfl_xor(ssq, 32, 64);
            if (lane < 16) {
                atomicAdd(&stats[col], ssum);
                atomicAdd(&stats[DD + col], ssq);
            }
        }
    }
}

// ---------------- BN prep + apply ----------------
__global__ void k_bnprep(float* __restrict__ st, const float* __restrict__ gamma,
                         const float* __restrict__ beta) {
    int c = threadIdx.x;
    if (c < DD) {
        const float invn = 1.0f / (float)NN;
        float mean = st[c] * invn;
        float var = st[DD + c] * invn - mean * mean;
        float sc = gamma[c] * rsqrtf(var + BN_EPS);
        st[256 + c] = sc;
        st[384 + c] = beta[c] - mean * sc;
    }
}

// Applies BN+ReLU and writes xs = relu(bn(H)) * dis[node]  (pre-scaled for SGConv)
__global__ void k_bnrelu(const float* __restrict__ H, const float* __restrict__ st,
                         const float* __restrict__ dis, uint16_t* __restrict__ xb) {
    int idx = blockIdx.x * 256 + threadIdx.x;
    if (idx >= NN * 32) return;
    int node = idx >> 5, c4 = (idx & 31) << 2;
    float d = dis[node];
    float4 v = *(const float4*)(H + (size_t)node * DD + c4);
    float r0 = fmaxf(v.x * st[256 + c4 + 0] + st[384 + c4 + 0], 0.0f) * d;
    float r1 = fmaxf(v.y * st[256 + c4 + 1] + st[384 + c4 + 1], 0.0f) * d;
    float r2 = fmaxf(v.z * st[256 + c4 + 2] + st[384 + c4 + 2], 0.0f) * d;
    float r3 = fmaxf(v.w * st[256 + c4 + 3] + st[384 + c4 + 3], 0.0f) * d;
    ushort4 o;
    o.x = f2bf(r0); o.y = f2bf(r1); o.z = f2bf(r2); o.w = f2bf(r3);
    *(ushort4*)(xb + (size_t)node * DD + c4) = o;
}

// ---------------- launch ----------------
extern "C" void kernel_launch(void* const* d_in, const int* in_sizes, int n_in,
                              void* d_out, int out_size, void* d_ws, size_t ws_size,
                              hipStream_t stream) {
    const int* x_idx   = (const int*)d_in[0];
    const int* ei      = (const int*)d_in[1];
    const float* emb   = (const float*)d_in[2];
    const float* W_out = (const float*)d_in[3];
    const float* W_root= (const float*)d_in[4];
    const float* g0    = (const float*)d_in[5];
    const float* be0   = (const float*)d_in[6];
    const float* W1    = (const float*)d_in[7];
    const float* b1    = (const float*)d_in[8];
    const float* g1    = (const float*)d_in[9];
    const float* be1   = (const float*)d_in[10];
    const float* W2    = (const float*)d_in[11];
    const float* b2    = (const float*)d_in[12];
    float* out = (float*)d_out;

    char* ws = (char*)d_ws;
    size_t o = 0;
    auto carve = [&](size_t bytes) -> void* {
        void* p = ws + o;
        o = (o + bytes + 255) & ~(size_t)255;
        return p;
    };
    int* cnt      = (int*)carve((size_t)NN * 4);
    int* fillp    = (int*)carve((size_t)NN * 4);
    int* off      = (int*)carve((size_t)(NN + 1) * 4);
    int* bsum     = (int*)carve(256 * 4);
    float* deginv = (float*)carve((size_t)NN * 4);
    float* dis    = (float*)carve((size_t)NN * 4);
    int* csr_row  = (int*)carve((size_t)NE * 4);
    uint16_t* xb  = (uint16_t*)carve((size_t)NN * DD * 2);
    uint16_t* aggb= (uint16_t*)carve((size_t)NN * DD * 2);
    float* st0    = (float*)carve(512 * 4);
    float* st1    = (float*)carve(512 * 4);

    hipMemsetAsync(cnt, 0, (size_t)NN * 4, stream);
    hipMemsetAsync(fillp, 0, (size_t)NN * 4, stream);
    hipMemsetAsync(st0, 0, 256 * 4, stream);
    hipMemsetAsync(st1, 0, 256 * 4, stream);

    const int EB = (NE + 255) / 256;
    const int NB = (NN + 255) / 256;        // 196
    const int GB = (NN + 127) / 128;        // 391 GEMM tiles
    const int AB = (NN + 3) / 4;            // 12500 agg blocks
    const int VB = (NN * 32 + 255) / 256;   // 6250 elementwise blocks

    k_count<<<EB, 256, 0, stream>>>(ei + NE, cnt);
    k_bsum<<<NB, 256, 0, stream>>>(cnt, bsum);
    k_bscan<<<1, 256, 0, stream>>>(bsum, NB);
    k_off<<<NB, 256, 0, stream>>>(cnt, bsum, off, deginv, dis);
    k_fill<<<EB, 256, 0, stream>>>(ei, off, fillp, csr_row);
    k_gather<<<VB, 256, 0, stream>>>(x_idx, emb, xb);

    // layer 0: ClusterGCN -> BN -> ReLU (bnrelu output pre-scaled by dis)
    k_agg<0><<<AB, 256, 0, stream>>>(xb, off, csr_row, deginv, dis, aggb);
    k_gemm<true, true, false><<<GB, 256, 0, stream>>>(aggb, xb, W_out, W_root, nullptr, out, st0);
    k_bnprep<<<1, 128, 0, stream>>>(st0, g0, be0);
    k_bnrelu<<<VB, 256, 0, stream>>>(out, st0, dis, xb);

    // layer 1: SGConv -> BN -> ReLU (input xb is pre-scaled xs)
    k_agg<1><<<AB, 256, 0, stream>>>(xb, off, csr_row, deginv, dis, aggb);
    k_gemm<false, true, true><<<GB, 256, 0, stream>>>(aggb, nullptr, W1, nullptr, b1, out, st1);
    k_bnprep<<<1, 128, 0, stream>>>(st1, g1, be1);
    k_bnrelu<<<VB, 256, 0, stream>>>(out, st1, dis, xb);

    // layer 2: final SGConv -> d_out
    k_agg<1><<<AB, 256, 0, stream>>>(xb, off, csr_row, deginv, dis, aggb);
    k_gemm<false, false, true><<<GB, 256, 0, stream>>>(aggb, nullptr, W2, nullptr, b2, out, nullptr);
}

// Round 3
// 266.066 us; speedup vs baseline: 1.4011x; 1.0064x over previous
//
#include <hip/hip_runtime.h>
#include <stdint.h>

#define NN 50000
#define NE 600000
#define DD 128
#define BN_EPS 1e-5f

typedef __attribute__((ext_vector_type(8))) short short8;
typedef __attribute__((ext_vector_type(4))) float f32x4;

__device__ __forceinline__ float bf2f(uint16_t u) {
    union { uint32_t u; float f; } v; v.u = ((uint32_t)u) << 16; return v.f;
}
__device__ __forceinline__ uint16_t f2bf(float f) {
    union { float f; uint32_t u; } v; v.f = f;
    return (uint16_t)((v.u + 0x7FFFu + ((v.u >> 16) & 1u)) >> 16);
}
__device__ __forceinline__ float lo16(uint32_t v) { return bf2f((uint16_t)(v & 0xFFFFu)); }
__device__ __forceinline__ float hi16(uint32_t v) { return bf2f((uint16_t)(v >> 16)); }

// ---------------- CSR build (atomic segment allocator; order-free) ----------------
__global__ void k_count(const int* __restrict__ col, int* __restrict__ cnt) {
    int e = blockIdx.x * 256 + threadIdx.x;
    if (e < NE) atomicAdd(&cnt[col[e]], 1);
}

// Per node: allocate padded segment (multiple of 8), write base to off+fillp,
// compute deg scalars, fill pad slots with the zero-row index NN.
__global__ void k_alloc(const int* __restrict__ cnt, int* __restrict__ cursor,
                        int* __restrict__ off, int* __restrict__ fillp,
                        float* __restrict__ deginv, float* __restrict__ dis,
                        int* __restrict__ csr_row) {
    int i = blockIdx.x * 256 + threadIdx.x;
    if (i >= NN) return;
    int deg = cnt[i];
    int padded = (deg + 7) & ~7;
    int base = atomicAdd(cursor, padded);
    off[i] = base;
    fillp[i] = base;
    deginv[i] = 1.0f / fmaxf((float)deg, 1.0f);   // ClusterGCN 1/deg
    dis[i] = rsqrtf((float)deg + 1.0f);           // SGConv D^{-1/2} incl self-loop
    for (int p = deg; p < padded; ++p) csr_row[base + p] = NN;  // pad -> zero row
}

__global__ void k_fill(const int* __restrict__ ei, int* __restrict__ fillp,
                       int* __restrict__ csr_row) {
    int e = blockIdx.x * 256 + threadIdx.x;
    if (e < NE) {
        int c = ei[NE + e];
        int p = atomicAdd(&fillp[c], 1);
        csr_row[p] = ei[e];
    }
}

// ---------------- gather + fp32->bf16 (row NN = zeros) ----------------
__global__ void k_gather(const int* __restrict__ x_idx, const float* __restrict__ emb,
                         uint16_t* __restrict__ xb) {
    int idx = blockIdx.x * 256 + threadIdx.x;  // (NN+1)*32 threads, 4 elems each
    if (idx >= (NN + 1) * 32) return;
    int node = idx >> 5, c4 = (idx & 31) << 2;
    ushort4 o;
    if (node == NN) {
        o.x = 0; o.y = 0; o.z = 0; o.w = 0;
    } else {
        int src = x_idx[node];
        float4 v = *(const float4*)(emb + (size_t)src * DD + c4);
        o.x = f2bf(v.x); o.y = f2bf(v.y); o.z = f2bf(v.z); o.w = f2bf(v.w);
    }
    *(ushort4*)(xb + (size_t)node * DD + c4) = o;
}

// ---------------- aggregation (1 wave = 1 node, 8-deep gather MLP) ----------------
// MODE 0: agg[c] = deginv[c] * sum_e x[row_e]                       (x = xb, unscaled)
// MODE 1: agg[c] = dis[c] * (xs[c] + sum_e xs[row_e]), xs pre-scaled by dis on producer
template<int MODE>
__global__ __launch_bounds__(256)
void k_agg(const uint16_t* __restrict__ xb, const int* __restrict__ off,
           const int* __restrict__ cnt, const int* __restrict__ csr_row,
           const float* __restrict__ deginv, const float* __restrict__ dis,
           uint16_t* __restrict__ aggb) {
    int node = blockIdx.x * 4 + (threadIdx.x >> 6);
    if (node >= NN) return;
    int lane = threadIdx.x & 63;
    const uint32_t* __restrict__ xw = (const uint32_t*)xb;
    float a0 = 0.0f, a1 = 0.0f;
    if (MODE == 1) {
        uint32_t v = xw[(size_t)node * 64 + lane];  // self term: xs[c]
        a0 = lo16(v); a1 = hi16(v);
    }
    int s = off[node];
    int padded = (cnt[node] + 7) & ~7;
    for (int base = 0; base < padded; base += 64) {
        int rem = min(padded - base, 64);           // multiple of 8
        int idxv = (lane < rem) ? csr_row[s + base + lane] : NN;
        for (int i = 0; i < rem; i += 8) {
            uint32_t v[8];
            #pragma unroll
            for (int u = 0; u < 8; ++u) {
                int r = __builtin_amdgcn_readlane(idxv, i + u);
                v[u] = xw[(size_t)r * 64 + lane];
            }
            #pragma unroll
            for (int u = 0; u < 8; ++u) { a0 += lo16(v[u]); a1 += hi16(v[u]); }
        }
    }
    float sc = (MODE == 1) ? dis[node] : deginv[node];
    a0 *= sc; a1 *= sc;
    uint32_t o = (uint32_t)f2bf(a0) | ((uint32_t)f2bf(a1) << 16);
    *(uint32_t*)(aggb + (size_t)node * DD + lane * 2) = o;
}

// ---------------- MFMA GEMM: H = A1@W1^T (+ A2@W2^T) (+bias), BN stats ----------------
// STORE_BF16: write H as bf16 (layers 0/1, consumed by bnrelu); else fp32 (final out).
template<bool DUAL, bool STATS, bool BIAS, bool STORE_BF16>
__global__ __launch_bounds__(256, 2)
void k_gemm(const uint16_t* __restrict__ A1, const uint16_t* __restrict__ A2,
            const float* __restrict__ W1, const float* __restrict__ W2,
            const float* __restrict__ bias, float* __restrict__ Hf,
            uint16_t* __restrict__ Hb, float* __restrict__ stats) {
    __shared__ uint16_t Alds[128 * 128];
    __shared__ uint16_t Wlds[128 * 128];
    const int t = threadIdx.x;
    const int lane = t & 63, wid = t >> 6;
    const int wm = (wid >> 1) * 64, wn = (wid & 1) * 64;
    const int m0 = blockIdx.x * 128;
    f32x4 zero = {0.0f, 0.0f, 0.0f, 0.0f};
    f32x4 acc[4][4];
    #pragma unroll
    for (int m = 0; m < 4; ++m)
        #pragma unroll
        for (int n = 0; n < 4; ++n) acc[m][n] = zero;

    const int NP = DUAL ? 2 : 1;
    for (int p = 0; p < NP; ++p) {
        const uint16_t* A = (DUAL && p) ? A2 : A1;
        const float* W = (DUAL && p) ? W2 : W1;
        if (p) __syncthreads();
        // stage A tile: 2048 16B chunks, XOR-swizzled rows (G4)
        #pragma unroll
        for (int it = 0; it < 8; ++it) {
            int idx = it * 256 + t;
            int row = idx >> 4, c16 = idx & 15;
            uint32_t boff = (uint32_t)(row * 256 + ((c16 * 16) ^ ((row & 7) << 4)));
            uint4 v = make_uint4(0u, 0u, 0u, 0u);
            if (m0 + row < NN)
                v = *(const uint4*)(A + (size_t)(m0 + row) * DD + c16 * 8);
            *(uint4*)((char*)Alds + boff) = v;
        }
        // stage W tile: fp32 -> bf16, same swizzle
        #pragma unroll
        for (int it = 0; it < 8; ++it) {
            int idx = it * 256 + t;
            int row = idx >> 4, c8 = idx & 15;
            const float* wp = W + row * DD + c8 * 8;
            float4 v0 = *(const float4*)(wp);
            float4 v1 = *(const float4*)(wp + 4);
            uint4 pk;
            pk.x = (uint32_t)f2bf(v0.x) | ((uint32_t)f2bf(v0.y) << 16);
            pk.y = (uint32_t)f2bf(v0.z) | ((uint32_t)f2bf(v0.w) << 16);
            pk.z = (uint32_t)f2bf(v1.x) | ((uint32_t)f2bf(v1.y) << 16);
            pk.w = (uint32_t)f2bf(v1.z) | ((uint32_t)f2bf(v1.w) << 16);
            uint32_t boff = (uint32_t)(row * 256 + ((c8 * 16) ^ ((row & 7) << 4)));
            *(uint4*)((char*)Wlds + boff) = pk;
        }
        __syncthreads();
        #pragma unroll
        for (int ks = 0; ks < 4; ++ks) {
            short8 a[4], b[4];
            int kb = ks * 64 + ((lane >> 4) << 4);   // byte offset of this lane's 8 bf16
            #pragma unroll
            for (int m = 0; m < 4; ++m) {
                int row = wm + m * 16 + (lane & 15);
                a[m] = *(const short8*)((const char*)Alds + row * 256 + (kb ^ ((row & 7) << 4)));
            }
            #pragma unroll
            for (int n = 0; n < 4; ++n) {
                int row = wn + n * 16 + (lane & 15);
                b[n] = *(const short8*)((const char*)Wlds + row * 256 + (kb ^ ((row & 7) << 4)));
            }
            #pragma unroll
            for (int m = 0; m < 4; ++m)
                #pragma unroll
                for (int n = 0; n < 4; ++n)
                    acc[m][n] = __builtin_amdgcn_mfma_f32_16x16x32_bf16(a[m], b[n], acc[m][n], 0, 0, 0);
        }
    }
    // epilogue: bias, store (bf16 or fp32), BN stats (sum/sumsq per channel)
    #pragma unroll
    for (int n = 0; n < 4; ++n) {
        int col = wn + n * 16 + (lane & 15);
        float bb = BIAS ? bias[col] : 0.0f;
        float ssum = 0.0f, ssq = 0.0f;
        #pragma unroll
        for (int m = 0; m < 4; ++m) {
            int rbase = m0 + wm + m * 16 + ((lane >> 4) << 2);
            #pragma unroll
            for (int i = 0; i < 4; ++i) {
                int gr = rbase + i;
                if (gr < NN) {
                    float v = acc[m][n][i] + bb;
                    if (STORE_BF16) Hb[(size_t)gr * DD + col] = f2bf(v);
                    else            Hf[(size_t)gr * DD + col] = v;
                    ssum += v; ssq += v * v;
                }
            }
        }
        if (STATS) {
            ssum += __shfl_xor(ssum, 16, 64);
            ssum += __shfl_xor(ssum, 32, 64);
            ssq  += __shfl_xor(ssq, 16, 64);
            ssq  += __shfl_xor(ssq, 32, 64);
            if (lane < 16) {
                atomicAdd(&stats[col], ssum);
                atomicAdd(&stats[DD + col], ssq);
            }
        }
    }
}

// ---------------- fused BN prep + apply + ReLU + dis pre-scale ----------------
// Reads bf16 H; writes xs = relu(bn(H)) * dis[node] as bf16.
__global__ __launch_bounds__(256)
void k_bnrelu(const uint16_t* __restrict__ Hb, const float* __restrict__ st,
              const float* __restrict__ gamma, const float* __restrict__ beta,
              const float* __restrict__ dis, uint16_t* __restrict__ xb) {
    __shared__ float s_sc[128], s_of[128];
    int t = threadIdx.x;
    if (t < 128) {
        const float invn = 1.0f / (float)NN;
        float mean = st[t] * invn;
        float var = st[DD + t] * invn - mean * mean;
        float sc = gamma[t] * rsqrtf(var + BN_EPS);
        s_sc[t] = sc;
        s_of[t] = beta[t] - mean * sc;
    }
    __syncthreads();
    int idx = blockIdx.x * 256 + t;              // 16 threads/row, 8 elems/thread
    int node = idx >> 4, c8 = (idx & 15) << 3;
    if (node >= NN) return;
    float d = dis[node];
    uint4 h = *(const uint4*)(Hb + (size_t)node * DD + c8);
    uint32_t hw[4] = {h.x, h.y, h.z, h.w};
    uint32_t ow[4];
    #pragma unroll
    for (int j = 0; j < 4; ++j) {
        int c = c8 + j * 2;
        float v0 = fmaxf(lo16(hw[j]) * s_sc[c]     + s_of[c],     0.0f) * d;
        float v1 = fmaxf(hi16(hw[j]) * s_sc[c + 1] + s_of[c + 1], 0.0f) * d;
        ow[j] = (uint32_t)f2bf(v0) | ((uint32_t)f2bf(v1) << 16);
    }
    uint4 o = make_uint4(ow[0], ow[1], ow[2], ow[3]);
    *(uint4*)(xb + (size_t)node * DD + c8) = o;
}

// ---------------- launch ----------------
extern "C" void kernel_launch(void* const* d_in, const int* in_sizes, int n_in,
                              void* d_out, int out_size, void* d_ws, size_t ws_size,
                              hipStream_t stream) {
    const int* x_idx   = (const int*)d_in[0];
    const int* ei      = (const int*)d_in[1];
    const float* emb   = (const float*)d_in[2];
    const float* W_out = (const float*)d_in[3];
    const float* W_root= (const float*)d_in[4];
    const float* g0    = (const float*)d_in[5];
    const float* be0   = (const float*)d_in[6];
    const float* W1    = (const float*)d_in[7];
    const float* b1    = (const float*)d_in[8];
    const float* g1    = (const float*)d_in[9];
    const float* be1   = (const float*)d_in[10];
    const float* W2    = (const float*)d_in[11];
    const float* b2    = (const float*)d_in[12];
    float* out = (float*)d_out;

    char* ws = (char*)d_ws;
    size_t o = 0;
    auto carve = [&](size_t bytes) -> void* {
        void* p = ws + o;
        o = (o + bytes + 255) & ~(size_t)255;
        return p;
    };
    // zero-init group first (single memset)
    int* cnt      = (int*)carve((size_t)NN * 4);
    int* cursor   = (int*)carve(4);
    float* st0    = (float*)carve(256 * 4);
    float* st1    = (float*)carve(256 * 4);
    size_t zlen = o;
    // rest
    int* fillp    = (int*)carve((size_t)NN * 4);
    int* off      = (int*)carve((size_t)NN * 4);
    float* deginv = (float*)carve((size_t)NN * 4);
    float* dis    = (float*)carve((size_t)NN * 4);
    int* csr_row  = (int*)carve((size_t)(NE + NN * 8) * 4);   // padded segments
    uint16_t* xb  = (uint16_t*)carve((size_t)(NN + 1) * DD * 2); // +1 zero row
    uint16_t* aggb= (uint16_t*)carve((size_t)NN * DD * 2);
    uint16_t* hb  = (uint16_t*)carve((size_t)NN * DD * 2);

    hipMemsetAsync(ws, 0, zlen, stream);

    const int EB = (NE + 255) / 256;
    const int NB = (NN + 255) / 256;            // 196
    const int GB = (NN + 127) / 128;            // 391 GEMM tiles
    const int AB = (NN + 3) / 4;                // 12500 agg blocks
    const int VB = ((NN + 1) * 32 + 255) / 256; // gather blocks
    const int BB = (NN * 16 + 255) / 256;       // 3125 bnrelu blocks

    k_count<<<EB, 256, 0, stream>>>(ei + NE, cnt);
    k_alloc<<<NB, 256, 0, stream>>>(cnt, cursor, off, fillp, deginv, dis, csr_row);
    k_fill<<<EB, 256, 0, stream>>>(ei, fillp, csr_row);
    k_gather<<<VB, 256, 0, stream>>>(x_idx, emb, xb);

    // layer 0: ClusterGCN -> BN -> ReLU (bnrelu output pre-scaled by dis)
    k_agg<0><<<AB, 256, 0, stream>>>(xb, off, cnt, csr_row, deginv, dis, aggb);
    k_gemm<true, true, false, true><<<GB, 256, 0, stream>>>(
        aggb, xb, W_out, W_root, nullptr, nullptr, hb, st0);
    k_bnrelu<<<BB, 256, 0, stream>>>(hb, st0, g0, be0, dis, xb);

    // layer 1: SGConv -> BN -> ReLU (input xb is pre-scaled xs)
    k_agg<1><<<AB, 256, 0, stream>>>(xb, off, cnt, csr_row, deginv, dis, aggb);
    k_gemm<false, true, true, true><<<GB, 256, 0, stream>>>(
        aggb, nullptr, W1, nullptr, b1, nullptr, hb, st1);
    k_bnrelu<<<BB, 256, 0, stream>>>(hb, st1, g1, be1, dis, xb);

    // layer 2: final SGConv -> d_out (fp32)
    k_agg<1><<<AB, 256, 0, stream>>>(xb, off, cnt, csr_row, deginv, dis, aggb);
    k_gemm<false, false, true, false><<<GB, 256, 0, stream>>>(
        aggb, nullptr, W2, nullptr, b2, out, nullptr, nullptr);
}